// Round 4
// baseline (234.090 us; speedup 1.0000x reference)
//
#include <hip/hip_runtime.h>

#define LBL 32
#define NPIX (736 * 736)   // 541696
#define NQ (NPIX / 4)      // 135424 = 529 * 256 float4-quads per batch
#define NB 529             // blocks per batch (1 quad per thread)
#define BATCH 8
#define DELTA_AGG 0.5f
#define DELTA_DIS 1.5f
#define REG_W 0.001f

// ws layout (floats), ~3.8 MB total:
//  partA: [PA_BASE, +8*529*160)  per (batch,block): cnt[32] ([0]=saw-label-0 flag), sum[32*4]
//  red:   [RED_BASE, +8*192)     per batch: cnt_k[32], mean[32*4]
//  partC: [PC_BASE, +8*529*64)   per (batch,block): val[32], cnt[32]
#define PA_BASE 0
#define RED_BASE (BATCH * NB * 160)            // 677120
#define PC_BASE (RED_BASE + BATCH * 192)       // 678656

// -------- Pass A: per-(batch,label) kernel-region count + emb sums ----------
__global__ __launch_bounds__(256) void kA(
    const float* __restrict__ emb, const int* __restrict__ inst,
    const float* __restrict__ kern, const float* __restrict__ mask,
    float* __restrict__ ws) {
  const int b = blockIdx.y;
  __shared__ float s_cnt[LBL];   // [0] is the "saw label 0" flag
  __shared__ float s_sum[LBL * 4];
  if (threadIdx.x < LBL) s_cnt[threadIdx.x] = 0.f;
  if (threadIdx.x < LBL * 4) s_sum[threadIdx.x] = 0.f;
  __syncthreads();

  const long base = (long)b * NPIX;
  const int q = blockIdx.x * 256 + threadIdx.x;  // one quad per thread
  const int4 iv = ((const int4*)(inst + base))[q];
  const float4 kv = ((const float4*)(kern + base))[q];
  const float4 mv = ((const float4*)(mask + base))[q];
  const float* eb = emb + (long)b * 4 * NPIX;
  const float4 e0 = ((const float4*)(eb))[q];
  const float4 e1 = ((const float4*)(eb + NPIX))[q];
  const float4 e2 = ((const float4*)(eb + 2 * NPIX))[q];
  const float4 e3 = ((const float4*)(eb + 3 * NPIX))[q];

  const int labs[4] = {iv.x, iv.y, iv.z, iv.w};
  const float ks[4] = {kv.x, kv.y, kv.z, kv.w};
  const float ms[4] = {mv.x, mv.y, mv.z, mv.w};
  const float c0[4] = {e0.x, e0.y, e0.z, e0.w};
  const float c1[4] = {e1.x, e1.y, e1.z, e1.w};
  const float c2[4] = {e2.x, e2.y, e2.z, e2.w};
  const float c3[4] = {e3.x, e3.y, e3.z, e3.w};

  bool has0 = false;
#pragma unroll
  for (int j = 0; j < 4; j++) {
    const int lk = (ms[j] > 0.5f && ks[j] > 0.5f) ? labs[j] : 0;
    if (lk > 0) {
      atomicAdd(&s_cnt[lk], 1.0f);
      atomicAdd(&s_sum[lk * 4 + 0], c0[j]);
      atomicAdd(&s_sum[lk * 4 + 1], c1[j]);
      atomicAdd(&s_sum[lk * 4 + 2], c2[j]);
      atomicAdd(&s_sum[lk * 4 + 3], c3[j]);
    } else {
      has0 = true;
    }
  }
  if (has0) s_cnt[0] = 1.0f;  // benign race: all writers store 1
  __syncthreads();

  // Plain coalesced partial store — NO global atomics.
  float* po = ws + PA_BASE + (size_t)(b * NB + blockIdx.x) * 160;
  const int t = threadIdx.x;
  if (t < 160) po[t] = (t < 32) ? s_cnt[t] : s_sum[t - 32];
}

// -------- Reduce A partials -> cnt_k + means (one block per batch) ----------
__global__ __launch_bounds__(1024) void kB(float* __restrict__ ws) {
  const int b = blockIdx.x, t = threadIdx.x;
  const int c = t / 160, e = t - c * 160;  // 6 chunks x 160 elems (960 active)
  __shared__ float red[6 * 160];
  if (c < 6) {
    const float* pa = ws + PA_BASE + (size_t)b * NB * 160 + e;
    float s = 0.f;
    for (int g = c; g < NB; g += 6) s += pa[(size_t)g * 160];
    red[c * 160 + e] = s;
  }
  __syncthreads();
  __shared__ float tot[160];
  if (t < 160) {
    float s = 0.f;
#pragma unroll
    for (int k = 0; k < 6; k++) s += red[k * 160 + t];
    tot[t] = s;
  }
  __syncthreads();
  if (t < 160) {
    float* rd = ws + RED_BASE + b * 192;
    if (t < 32) {
      rd[t] = tot[t];  // cnt_k ([0] = presence-flag sum)
    } else {
      const int l = (t - 32) >> 2;
      rd[t] = (l == 0) ? 0.f : tot[t] / fmaxf(tot[l], 1.0f);  // mean
    }
  }
}

// -------- Pass C: aggregation loss segment sums -----------------------------
__global__ __launch_bounds__(256) void kC(
    const float* __restrict__ emb, const int* __restrict__ inst,
    const float* __restrict__ mask, float* __restrict__ ws) {
  const int b = blockIdx.y;
  __shared__ float s_mean[LBL * 4];
  __shared__ float s_val[LBL];
  __shared__ float s_cnt[LBL];
  const float* rd = ws + RED_BASE + b * 192;
  if (threadIdx.x < LBL * 4) s_mean[threadIdx.x] = rd[32 + threadIdx.x];
  if (threadIdx.x < LBL) {
    s_val[threadIdx.x] = 0.f;
    s_cnt[threadIdx.x] = 0.f;
  }
  __syncthreads();

  const long base = (long)b * NPIX;
  const int q = blockIdx.x * 256 + threadIdx.x;
  const int4 iv = ((const int4*)(inst + base))[q];
  const float4 mv = ((const float4*)(mask + base))[q];
  const float* eb = emb + (long)b * 4 * NPIX;
  const float4 e0 = ((const float4*)(eb))[q];
  const float4 e1 = ((const float4*)(eb + NPIX))[q];
  const float4 e2 = ((const float4*)(eb + 2 * NPIX))[q];
  const float4 e3 = ((const float4*)(eb + 3 * NPIX))[q];

  const int labs[4] = {iv.x, iv.y, iv.z, iv.w};
  const float ms[4] = {mv.x, mv.y, mv.z, mv.w};
  const float c0[4] = {e0.x, e0.y, e0.z, e0.w};
  const float c1[4] = {e1.x, e1.y, e1.z, e1.w};
  const float c2[4] = {e2.x, e2.y, e2.z, e2.w};
  const float c3[4] = {e3.x, e3.y, e3.z, e3.w};

#pragma unroll
  for (int j = 0; j < 4; j++) {
    const int li = (ms[j] > 0.5f) ? labs[j] : 0;
    if (li > 0) {  // label 0 excluded from l_agg (nz mask)
      const float d0 = c0[j] - s_mean[li * 4 + 0];
      const float d1 = c1[j] - s_mean[li * 4 + 1];
      const float d2 = c2[j] - s_mean[li * 4 + 2];
      const float d3 = c3[j] - s_mean[li * 4 + 3];
      const float sq = d0 * d0 + d1 * d1 + d2 * d2 + d3 * d3;
      const float dist = (sq > 0.f) ? sqrtf(sq) : 0.f;
      const float tt = fmaxf(dist - DELTA_AGG, 0.f);
      atomicAdd(&s_val[li], logf(fmaf(tt, tt, 1.0f)));
      atomicAdd(&s_cnt[li], 1.0f);
    }
  }
  __syncthreads();
  float* po = ws + PC_BASE + (size_t)(b * NB + blockIdx.x) * 64;
  const int t = threadIdx.x;
  if (t < 64) po[t] = (t < 32) ? s_val[t] : s_cnt[t - 32];
}

// -------- Reduce C + finalize (one block per batch) -------------------------
__global__ __launch_bounds__(256) void kD(const float* __restrict__ ws,
                                          float* __restrict__ out) {
  const int b = blockIdx.x;
  const int t = threadIdx.x;
  const int c = t >> 6, e = t & 63;  // 4 chunks x 64 elems
  const float* pc = ws + PC_BASE + (size_t)b * NB * 64 + e;
  float s = 0.f;
  for (int g = c; g < NB; g += 4) s += pc[(size_t)g * 64];
  __shared__ float red4[4][64];
  red4[c][e] = s;

  const float* rd = ws + RED_BASE + b * 192;
  __shared__ float sm[LBL * 4];
  __shared__ float sc[LBL];
  if (t >= 64 && t < 192) sm[t - 64] = rd[32 + (t - 64)];
  if (t >= 192 && t < 224) sc[t - 192] = rd[t - 192];
  __syncthreads();
  __shared__ float sv[64];  // [0,32)=sum_v, [32,64)=cnt_a
  if (t < 64) sv[t] = red4[0][t] + red4[1][t] + red4[2][t] + red4[3][t];
  __syncthreads();

  if (t < 64) {
    const int lane = t;
    const bool pres = (lane < LBL) && (sc[lane & 31] > 0.f) && (lane < LBL);
    const unsigned long long bal_p = __ballot((lane < LBL) && (sc[lane & 31] > 0.f));
    const int num_instance = __popcll(bal_p);
    const bool nz = pres && (lane > 0);
    const unsigned long long bal_nz = __ballot(nz);

    float agg = 0.f;
    if (nz) agg = sv[lane] / fmaxf(sv[32 + lane], 1.0f);

    float reg = 0.f;
    if (pres) {
      float sq = 0.f;
#pragma unroll
      for (int d = 0; d < 4; d++) sq += sm[lane * 4 + d] * sm[lane * 4 + d];
      const float nrm = (sq > 0.f) ? sqrtf(sq) : 0.f;
      reg = logf(nrm + 1.0f);
    }

    float dis = 0.f, npair = 0.f;
    for (int pi = lane; pi < LBL * LBL; pi += 64) {
      const int i = pi >> 5, j = pi & 31;
      if (i != j && ((bal_nz >> i) & 1ull) && ((bal_nz >> j) & 1ull)) {
        float sq = 0.f;
#pragma unroll
        for (int d = 0; d < 4; d++) {
          const float df = sm[i * 4 + d] - sm[j * 4 + d];
          sq += df * df;
        }
        const float pdist = (sq > 0.f) ? sqrtf(sq) : 0.f;
        const float tt = fmaxf(2.0f * DELTA_DIS - pdist, 0.f);
        dis += logf(fmaf(tt, tt, 1.0f));
        npair += 1.0f;
      }
    }

#pragma unroll
    for (int o = 32; o > 0; o >>= 1) {
      agg += __shfl_down(agg, o);
      reg += __shfl_down(reg, o);
      dis += __shfl_down(dis, o);
      npair += __shfl_down(npair, o);
    }

    if (lane == 0) {
      const float l_agg = agg / fmaxf((float)(num_instance - 1), 1.0f);
      const float l_dis = (num_instance > 2) ? dis / fmaxf(npair, 1.0f) : 0.f;
      const float l_reg = reg / fmaxf((float)num_instance, 1.0f) * REG_W;
      const float loss = l_agg + l_dis + l_reg;
      out[b] = (num_instance <= 1) ? 0.f : loss;
    }
  }
}

extern "C" void kernel_launch(void* const* d_in, const int* in_sizes, int n_in,
                              void* d_out, int out_size, void* d_ws,
                              size_t ws_size, hipStream_t stream) {
  const float* emb = (const float*)d_in[0];
  const int* instance = (const int*)d_in[1];
  const float* kern = (const float*)d_in[2];
  const float* mask = (const float*)d_in[3];
  float* out = (float*)d_out;
  float* ws = (float*)d_ws;

  // No memset: every ws word we read is plain-stored by a prior kernel.
  dim3 grid(NB, BATCH);  // 4232 blocks, one float4-quad per thread
  kA<<<grid, 256, 0, stream>>>(emb, instance, kern, mask, ws);
  kB<<<BATCH, 1024, 0, stream>>>(ws);
  kC<<<grid, 256, 0, stream>>>(emb, instance, mask, ws);
  kD<<<BATCH, 256, 0, stream>>>(ws, out);
}